// Round 1
// baseline (1825.910 us; speedup 1.0000x reference)
//
#include <hip/hip_runtime.h>

#define N_NODES  100000
#define N_EDGES  1600000
#define N_GRAPHS 128
#define HID      64

// ---------------- Layer-1 edge scatter: agg1[dst] += x[src], 3 floats ----------------
__global__ __launch_bounds__(256) void scatter3(const float* __restrict__ x,
                                                const int* __restrict__ src,
                                                const int* __restrict__ dst,
                                                float* __restrict__ agg) {
    int e = blockIdx.x * blockDim.x + threadIdx.x;
    if (e >= N_EDGES) return;
    int s = src[e], d = dst[e];
    float x0 = x[s * 3 + 0], x1 = x[s * 3 + 1], x2 = x[s * 3 + 2];
    atomicAdd(&agg[d * 3 + 0], x0);
    atomicAdd(&agg[d * 3 + 1], x1);
    atomicAdd(&agg[d * 3 + 2], x2);
}

// ---------------- Node MLP 1: h1 = relu(relu((x+agg) @ W1a + b1a) @ W1b + b1b) ----------------
__global__ __launch_bounds__(256) void mlp1(const float* __restrict__ x,
                                            const float* __restrict__ agg,
                                            const float* __restrict__ W1a,
                                            const float* __restrict__ b1a,
                                            const float* __restrict__ W1b,
                                            const float* __restrict__ b1b,
                                            float* __restrict__ h1) {
    __shared__ float sWa[3 * 64];
    __shared__ float sWb[64 * 64];
    __shared__ float sba[64], sbb[64];
    __shared__ float st[4][64];

    int tid = threadIdx.x;
    for (int i = tid; i < 3 * 64; i += 256) sWa[i] = W1a[i];
    for (int i = tid; i < 64 * 64; i += 256) sWb[i] = W1b[i];
    if (tid < 64) { sba[tid] = b1a[tid]; sbb[tid] = b1b[tid]; }

    int ln = tid >> 6;   // 0..3 node within block
    int j  = tid & 63;   // output dim
    int n  = blockIdx.x * 4 + ln;

    __syncthreads();

    if (n < N_NODES) {
        float in0 = x[n * 3 + 0] + agg[n * 3 + 0];
        float in1 = x[n * 3 + 1] + agg[n * 3 + 1];
        float in2 = x[n * 3 + 2] + agg[n * 3 + 2];
        float t = sba[j] + in0 * sWa[0 * 64 + j] + in1 * sWa[1 * 64 + j] + in2 * sWa[2 * 64 + j];
        st[ln][j] = fmaxf(t, 0.0f);
    }
    __syncthreads();
    if (n < N_NODES) {
        float acc = sbb[j];
#pragma unroll
        for (int k = 0; k < 64; ++k) acc += st[ln][k] * sWb[k * 64 + j];
        h1[(long long)n * 64 + j] = fmaxf(acc, 0.0f);
    }
}

// ---------------- Layer-2 edge scatter: agg2[dst] += h1[src], 64 floats ----------------
// 16 threads per edge; each handles a float4 slice (coalesced 256B per edge).
__global__ __launch_bounds__(256) void scatter64(const float* __restrict__ h,
                                                 const int* __restrict__ src,
                                                 const int* __restrict__ dst,
                                                 float* __restrict__ agg) {
    int gid = blockIdx.x * blockDim.x + threadIdx.x;   // < 25.6M, fits int
    int e = gid >> 4;
    int g = gid & 15;
    if (e >= N_EDGES) return;
    int s = src[e], d = dst[e];
    const float4 v = *reinterpret_cast<const float4*>(&h[(long long)s * 64 + g * 4]);
    float* a = &agg[(long long)d * 64 + g * 4];
    atomicAdd(a + 0, v.x);
    atomicAdd(a + 1, v.y);
    atomicAdd(a + 2, v.z);
    atomicAdd(a + 3, v.w);
}

// ---------------- Node MLP 2: h2 = relu(relu((h1+agg2) @ W2a + b2a) @ W2b + b2b) ----------------
// NOTE: h2 may alias agg (read-before-write per (n,j) by the same thread) -> no __restrict__ there.
__global__ __launch_bounds__(256) void mlp2(const float* __restrict__ h1,
                                            const float* agg,
                                            const float* __restrict__ W2a,
                                            const float* __restrict__ b2a,
                                            const float* __restrict__ W2b,
                                            const float* __restrict__ b2b,
                                            float* h2) {
    __shared__ float sWa[64 * 64];
    __shared__ float sWb[64 * 64];
    __shared__ float sba[64], sbb[64];
    __shared__ float sin_[4][64];
    __shared__ float st[4][64];

    int tid = threadIdx.x;
    for (int i = tid; i < 64 * 64; i += 256) { sWa[i] = W2a[i]; sWb[i] = W2b[i]; }
    if (tid < 64) { sba[tid] = b2a[tid]; sbb[tid] = b2b[tid]; }

    int ln = tid >> 6;
    int j  = tid & 63;
    int n  = blockIdx.x * 4 + ln;

    float inv = 0.0f;
    if (n < N_NODES) inv = h1[(long long)n * 64 + j] + agg[(long long)n * 64 + j];

    __syncthreads();            // weights + biases loaded
    sin_[ln][j] = inv;
    __syncthreads();            // input row staged

    float t = sba[j];
#pragma unroll
    for (int k = 0; k < 64; ++k) t += sin_[ln][k] * sWa[k * 64 + j];
    st[ln][j] = fmaxf(t, 0.0f);
    __syncthreads();            // hidden row staged

    if (n < N_NODES) {
        float acc = sbb[j];
#pragma unroll
        for (int k = 0; k < 64; ++k) acc += st[ln][k] * sWb[k * 64 + j];
        h2[(long long)n * 64 + j] = fmaxf(acc, 0.0f);
    }
}

// ---------------- Global mean pool: one block per graph, binary search on sorted batch ----------------
__global__ __launch_bounds__(256) void pool(const float* __restrict__ h2,
                                            const int* __restrict__ batch,
                                            float* __restrict__ out) {
    int g = blockIdx.x;

    // lower_bound(batch, g) and lower_bound(batch, g+1)
    int lo = 0, hi = N_NODES;
    while (lo < hi) { int mid = (lo + hi) >> 1; if (batch[mid] < g) lo = mid + 1; else hi = mid; }
    int start = lo;
    lo = start; hi = N_NODES;
    while (lo < hi) { int mid = (lo + hi) >> 1; if (batch[mid] < g + 1) lo = mid + 1; else hi = mid; }
    int end = lo;

    int j = threadIdx.x & 63;
    int r = threadIdx.x >> 6;   // 0..3
    float local = 0.0f;
    for (int n = start + r; n < end; n += 4)
        local += h2[(long long)n * 64 + j];

    __shared__ float red[4][64];
    red[r][j] = local;
    __syncthreads();
    if (r == 0) {
        float s = red[0][j] + red[1][j] + red[2][j] + red[3][j];
        float cnt = (float)((end - start) > 1 ? (end - start) : 1);
        out[g * 64 + j] = s / cnt;
    }
}

extern "C" void kernel_launch(void* const* d_in, const int* in_sizes, int n_in,
                              void* d_out, int out_size, void* d_ws, size_t ws_size,
                              hipStream_t stream) {
    const float* x    = (const float*)d_in[0];
    const int*   ei   = (const int*)d_in[1];   // [2, N_EDGES]
    const int*   bat  = (const int*)d_in[2];   // [N_NODES], sorted
    const float* W1a  = (const float*)d_in[3];
    const float* b1a  = (const float*)d_in[4];
    const float* W1b  = (const float*)d_in[5];
    const float* b1b  = (const float*)d_in[6];
    const float* W2a  = (const float*)d_in[7];
    const float* b2a  = (const float*)d_in[8];
    const float* W2b  = (const float*)d_in[9];
    const float* b2b  = (const float*)d_in[10];
    float* out = (float*)d_out;

    const int* src = ei;
    const int* dst = ei + N_EDGES;

    // workspace layout
    char* ws = (char*)d_ws;
    size_t agg1_bytes = (size_t)N_NODES * 3 * sizeof(float);
    agg1_bytes = (agg1_bytes + 255) & ~(size_t)255;
    float* agg1 = (float*)ws;
    float* h1   = (float*)(ws + agg1_bytes);
    float* agg2 = h1 + (size_t)N_NODES * 64;        // h2 aliases agg2 (safe: per-element RAW by same thread)
    float* h2   = agg2;

    hipMemsetAsync(agg1, 0, (size_t)N_NODES * 3 * sizeof(float), stream);
    hipMemsetAsync(agg2, 0, (size_t)N_NODES * 64 * sizeof(float), stream);

    scatter3<<<(N_EDGES + 255) / 256, 256, 0, stream>>>(x, src, dst, agg1);
    mlp1<<<(N_NODES + 3) / 4, 256, 0, stream>>>(x, agg1, W1a, b1a, W1b, b1b, h1);
    scatter64<<<(N_EDGES * 16) / 256, 256, 0, stream>>>(h1, src, dst, agg2);
    mlp2<<<(N_NODES + 3) / 4, 256, 0, stream>>>(h1, agg2, W2a, b2a, W2b, b2b, h2);
    pool<<<N_GRAPHS, 256, 0, stream>>>(h2, bat, out);
}

// Round 2
// 468.637 us; speedup vs baseline: 3.8962x; 3.8962x over previous
//
#include <hip/hip_runtime.h>

#define N_NODES  100000
#define N_EDGES  1600000
#define N_GRAPHS 128
#define HID      64
#define NGROUPS  (N_NODES / 4)          // 25000, N_NODES % 4 == 0
#define SCAN_CHUNK 1024
#define NB ((N_NODES + SCAN_CHUNK - 1) / SCAN_CHUNK)   // 98

// ---------------- CSR build ----------------
__global__ __launch_bounds__(256) void count_deg(const int* __restrict__ dst,
                                                 int* __restrict__ deg) {
    int e = blockIdx.x * blockDim.x + threadIdx.x;
    if (e >= N_EDGES) return;
    atomicAdd(&deg[dst[e]], 1);
}

// block partial sums of deg in 1024-chunks
__global__ __launch_bounds__(256) void scanA(const int* __restrict__ deg,
                                             int* __restrict__ partial) {
    int b = blockIdx.x, t = threadIdx.x;
    int idx = b * SCAN_CHUNK + t * 4;
    int sum = 0;
#pragma unroll
    for (int k = 0; k < 4; ++k)
        if (idx + k < N_NODES) sum += deg[idx + k];
    __shared__ int s[256];
    s[t] = sum;
    __syncthreads();
    for (int d = 128; d > 0; d >>= 1) {
        if (t < d) s[t] += s[t + d];
        __syncthreads();
    }
    if (t == 0) partial[b] = s[0];
}

// exclusive scan of NB partials, in place (one block of 128 threads; NB=98 < 128)
__global__ __launch_bounds__(128) void scanB(int* __restrict__ partial) {
    int t = threadIdx.x;
    __shared__ int s[128];
    s[t] = (t < NB) ? partial[t] : 0;
    __syncthreads();
    for (int d = 1; d < 128; d <<= 1) {
        int add = (t >= d) ? s[t - d] : 0;
        __syncthreads();
        s[t] += add;
        __syncthreads();
    }
    if (t < NB) partial[t] = (t == 0) ? 0 : s[t - 1];
}

// final exclusive scan: off[i], plus off[N_NODES] total
__global__ __launch_bounds__(256) void scanC(const int* __restrict__ deg,
                                             const int* __restrict__ partial,
                                             int* __restrict__ off) {
    int b = blockIdx.x, t = threadIdx.x;
    int idx = b * SCAN_CHUNK + t * 4;
    int v[4];
#pragma unroll
    for (int k = 0; k < 4; ++k)
        v[k] = (idx + k < N_NODES) ? deg[idx + k] : 0;
    int tsum = v[0] + v[1] + v[2] + v[3];
    __shared__ int s[256];
    s[t] = tsum;
    __syncthreads();
    for (int d = 1; d < 256; d <<= 1) {      // inclusive Hillis-Steele
        int add = (t >= d) ? s[t - d] : 0;
        __syncthreads();
        s[t] += add;
        __syncthreads();
    }
    int excl = (t == 0) ? 0 : s[t - 1];
    int p = partial[b] + excl;
#pragma unroll
    for (int k = 0; k < 4; ++k) {
        if (idx + k < N_NODES) off[idx + k] = p;
        p += v[k];
    }
    if (b == NB - 1 && t == 255) off[N_NODES] = partial[b] + s[255];
}

__global__ __launch_bounds__(256) void fill_csr(const int* __restrict__ src,
                                                const int* __restrict__ dst,
                                                const int* __restrict__ off,
                                                int* __restrict__ cur,
                                                int* __restrict__ esrc) {
    int e = blockIdx.x * blockDim.x + threadIdx.x;
    if (e >= N_EDGES) return;
    int d = dst[e];
    int p = off[d] + atomicAdd(&cur[d], 1);
    esrc[p] = src[e];
}

// ---------------- Layer 1 fused: gather(x) + MLP1 -> h1 ----------------
__global__ __launch_bounds__(256) void l1_fused(const float* __restrict__ x,
                                                const int* __restrict__ off,
                                                const int* __restrict__ esrc,
                                                const float* __restrict__ W1a,
                                                const float* __restrict__ b1a,
                                                const float* __restrict__ W1b,
                                                const float* __restrict__ b1b,
                                                float* __restrict__ h1) {
    __shared__ float sWa[3 * 64];
    __shared__ float sWb[64 * 64];
    __shared__ float sba[64], sbb[64];
    __shared__ float st[4][64];

    int tid = threadIdx.x;
    for (int i = tid; i < 3 * 64; i += 256) sWa[i] = W1a[i];
    for (int i = tid; i < 64 * 64; i += 256) sWb[i] = W1b[i];
    if (tid < 64) { sba[tid] = b1a[tid]; sbb[tid] = b1b[tid]; }
    __syncthreads();

    int ln = tid >> 6;   // node within group
    int j  = tid & 63;   // lane / output dim

    for (int grp = blockIdx.x; grp < NGROUPS; grp += gridDim.x) {
        int n = grp * 4 + ln;
        int start = off[n], end = off[n + 1];
        float a0 = 0.f, a1 = 0.f, a2 = 0.f;
        for (int e = start + j; e < end; e += 64) {
            int s = esrc[e];
            a0 += x[s * 3 + 0];
            a1 += x[s * 3 + 1];
            a2 += x[s * 3 + 2];
        }
#pragma unroll
        for (int d = 1; d < 64; d <<= 1) {
            a0 += __shfl_xor(a0, d);
            a1 += __shfl_xor(a1, d);
            a2 += __shfl_xor(a2, d);
        }
        float in0 = x[n * 3 + 0] + a0;
        float in1 = x[n * 3 + 1] + a1;
        float in2 = x[n * 3 + 2] + a2;
        float t = sba[j] + in0 * sWa[j] + in1 * sWa[64 + j] + in2 * sWa[128 + j];
        st[ln][j] = fmaxf(t, 0.0f);
        __syncthreads();
        float acc = sbb[j];
#pragma unroll
        for (int k = 0; k < 64; ++k) acc += st[ln][k] * sWb[k * 64 + j];
        h1[n * 64 + j] = fmaxf(acc, 0.0f);
        __syncthreads();   // st reused next iteration
    }
}

// ---------------- Layer 2 fused: gather(h1) + MLP2 -> h2 ----------------
__global__ __launch_bounds__(256) void l2_fused(const float* __restrict__ h1,
                                                const int* __restrict__ off,
                                                const int* __restrict__ esrc,
                                                const float* __restrict__ W2a,
                                                const float* __restrict__ b2a,
                                                const float* __restrict__ W2b,
                                                const float* __restrict__ b2b,
                                                float* __restrict__ h2) {
    __shared__ float sWa[64 * 64];
    __shared__ float sWb[64 * 64];
    __shared__ float sba[64], sbb[64];
    __shared__ float sin_[4][64];
    __shared__ float st[4][64];

    int tid = threadIdx.x;
    for (int i = tid; i < 64 * 64; i += 256) { sWa[i] = W2a[i]; sWb[i] = W2b[i]; }
    if (tid < 64) { sba[tid] = b2a[tid]; sbb[tid] = b2b[tid]; }
    __syncthreads();

    int ln = tid >> 6;
    int j  = tid & 63;

    for (int grp = blockIdx.x; grp < NGROUPS; grp += gridDim.x) {
        int n = grp * 4 + ln;
        int start = off[n], end = off[n + 1];

        float acc = h1[n * 64 + j];     // x_i + sum
        int e = start;
        for (; e + 4 <= end; e += 4) {
            int s0 = esrc[e], s1 = esrc[e + 1], s2 = esrc[e + 2], s3 = esrc[e + 3];
            float v0 = h1[s0 * 64 + j];
            float v1 = h1[s1 * 64 + j];
            float v2 = h1[s2 * 64 + j];
            float v3 = h1[s3 * 64 + j];
            acc += v0 + v1 + v2 + v3;
        }
        for (; e < end; ++e) acc += h1[esrc[e] * 64 + j];

        sin_[ln][j] = acc;
        __syncthreads();
        float t = sba[j];
#pragma unroll
        for (int k = 0; k < 64; ++k) t += sin_[ln][k] * sWa[k * 64 + j];
        st[ln][j] = fmaxf(t, 0.0f);
        __syncthreads();
        float o = sbb[j];
#pragma unroll
        for (int k = 0; k < 64; ++k) o += st[ln][k] * sWb[k * 64 + j];
        h2[n * 64 + j] = fmaxf(o, 0.0f);
        __syncthreads();
    }
}

// ---------------- Global mean pool ----------------
__global__ __launch_bounds__(256) void pool(const float* __restrict__ h2,
                                            const int* __restrict__ batch,
                                            float* __restrict__ out) {
    int g = blockIdx.x;
    int lo = 0, hi = N_NODES;
    while (lo < hi) { int mid = (lo + hi) >> 1; if (batch[mid] < g) lo = mid + 1; else hi = mid; }
    int start = lo;
    lo = start; hi = N_NODES;
    while (lo < hi) { int mid = (lo + hi) >> 1; if (batch[mid] < g + 1) lo = mid + 1; else hi = mid; }
    int end = lo;

    int j = threadIdx.x & 63;
    int r = threadIdx.x >> 6;
    float local = 0.0f;
    for (int n = start + r; n < end; n += 4)
        local += h2[n * 64 + j];

    __shared__ float red[4][64];
    red[r][j] = local;
    __syncthreads();
    if (r == 0) {
        float s = red[0][j] + red[1][j] + red[2][j] + red[3][j];
        float cnt = (float)((end - start) > 1 ? (end - start) : 1);
        out[g * 64 + j] = s / cnt;
    }
}

extern "C" void kernel_launch(void* const* d_in, const int* in_sizes, int n_in,
                              void* d_out, int out_size, void* d_ws, size_t ws_size,
                              hipStream_t stream) {
    const float* x    = (const float*)d_in[0];
    const int*   ei   = (const int*)d_in[1];
    const int*   bat  = (const int*)d_in[2];
    const float* W1a  = (const float*)d_in[3];
    const float* b1a  = (const float*)d_in[4];
    const float* W1b  = (const float*)d_in[5];
    const float* b1b  = (const float*)d_in[6];
    const float* W2a  = (const float*)d_in[7];
    const float* b2a  = (const float*)d_in[8];
    const float* W2b  = (const float*)d_in[9];
    const float* b2b  = (const float*)d_in[10];
    float* out = (float*)d_out;

    const int* src = ei;
    const int* dst = ei + N_EDGES;

    // workspace layout (256B-aligned slabs)
    char* ws = (char*)d_ws;
    auto alignup = [](size_t v) { return (v + 255) & ~(size_t)255; };
    int*   deg     = (int*)ws;                      ws += alignup((size_t)N_NODES * 4);
    int*   off     = (int*)ws;                      ws += alignup((size_t)(N_NODES + 1) * 4);
    int*   cur     = (int*)ws;                      ws += alignup((size_t)N_NODES * 4);
    int*   partial = (int*)ws;                      ws += alignup((size_t)NB * 4);
    int*   esrc    = (int*)ws;                      ws += alignup((size_t)N_EDGES * 4);
    float* h1      = (float*)ws;                    ws += alignup((size_t)N_NODES * HID * 4);
    float* h2      = (float*)ws;

    hipMemsetAsync(deg, 0, (size_t)N_NODES * 4, stream);
    hipMemsetAsync(cur, 0, (size_t)N_NODES * 4, stream);

    count_deg<<<(N_EDGES + 255) / 256, 256, 0, stream>>>(dst, deg);
    scanA<<<NB, 256, 0, stream>>>(deg, partial);
    scanB<<<1, 128, 0, stream>>>(partial);
    scanC<<<NB, 256, 0, stream>>>(deg, partial, off);
    fill_csr<<<(N_EDGES + 255) / 256, 256, 0, stream>>>(src, dst, off, cur, esrc);

    l1_fused<<<1024, 256, 0, stream>>>(x, off, esrc, W1a, b1a, W1b, b1b, h1);
    l2_fused<<<1024, 256, 0, stream>>>(h1, off, esrc, W2a, b2a, W2b, b2b, h2);
    pool<<<N_GRAPHS, 256, 0, stream>>>(h2, bat, out);
}

// Round 3
// 406.953 us; speedup vs baseline: 4.4868x; 1.1516x over previous
//
#include <hip/hip_runtime.h>

#define N_NODES  100000
#define N_EDGES  1600000
#define N_GRAPHS 128
#define HID      64
#define SCAN_CHUNK 1024
#define NB ((N_NODES + SCAN_CHUNK - 1) / SCAN_CHUNK)   // 98
#define BLK 1024
#define WPB (BLK / 64)          // 16 waves per block
#define NBLK 512                // 2 blocks/CU on 256 CUs

// ---------------- CSR build ----------------
__global__ __launch_bounds__(256) void count_deg(const int* __restrict__ dst,
                                                 int* __restrict__ deg) {
    int e = blockIdx.x * blockDim.x + threadIdx.x;
    if (e >= N_EDGES) return;
    atomicAdd(&deg[dst[e]], 1);
}

__global__ __launch_bounds__(256) void scanA(const int* __restrict__ deg,
                                             int* __restrict__ partial) {
    int b = blockIdx.x, t = threadIdx.x;
    int idx = b * SCAN_CHUNK + t * 4;
    int sum = 0;
#pragma unroll
    for (int k = 0; k < 4; ++k)
        if (idx + k < N_NODES) sum += deg[idx + k];
    __shared__ int s[256];
    s[t] = sum;
    __syncthreads();
    for (int d = 128; d > 0; d >>= 1) {
        if (t < d) s[t] += s[t + d];
        __syncthreads();
    }
    if (t == 0) partial[b] = s[0];
}

__global__ __launch_bounds__(128) void scanB(int* __restrict__ partial) {
    int t = threadIdx.x;
    __shared__ int s[128];
    s[t] = (t < NB) ? partial[t] : 0;
    __syncthreads();
    for (int d = 1; d < 128; d <<= 1) {
        int add = (t >= d) ? s[t - d] : 0;
        __syncthreads();
        s[t] += add;
        __syncthreads();
    }
    if (t < NB) partial[t] = (t == 0) ? 0 : s[t - 1];
}

__global__ __launch_bounds__(256) void scanC(const int* __restrict__ deg,
                                             const int* __restrict__ partial,
                                             int* __restrict__ off) {
    int b = blockIdx.x, t = threadIdx.x;
    int idx = b * SCAN_CHUNK + t * 4;
    int v[4];
#pragma unroll
    for (int k = 0; k < 4; ++k)
        v[k] = (idx + k < N_NODES) ? deg[idx + k] : 0;
    int tsum = v[0] + v[1] + v[2] + v[3];
    __shared__ int s[256];
    s[t] = tsum;
    __syncthreads();
    for (int d = 1; d < 256; d <<= 1) {
        int add = (t >= d) ? s[t - d] : 0;
        __syncthreads();
        s[t] += add;
        __syncthreads();
    }
    int excl = (t == 0) ? 0 : s[t - 1];
    int p = partial[b] + excl;
#pragma unroll
    for (int k = 0; k < 4; ++k) {
        if (idx + k < N_NODES) off[idx + k] = p;
        p += v[k];
    }
    if (b == NB - 1 && t == 255) off[N_NODES] = partial[b] + s[255];
}

__global__ __launch_bounds__(256) void fill_csr(const int* __restrict__ src,
                                                const int* __restrict__ dst,
                                                const int* __restrict__ off,
                                                int* __restrict__ cur,
                                                int* __restrict__ esrc) {
    int e = blockIdx.x * blockDim.x + threadIdx.x;
    if (e >= N_EDGES) return;
    int d = dst[e];
    int p = off[d] + atomicAdd(&cur[d], 1);
    esrc[p] = src[e];
}

// ---------------- Layer 1 fused: wave-per-node gather(x) + MLP1 -> h1 ----------------
__global__ __launch_bounds__(1024, 8) void l1_fused(const float* __restrict__ x,
                                                    const int* __restrict__ off,
                                                    const int* __restrict__ esrc,
                                                    const float* __restrict__ W1a,
                                                    const float* __restrict__ b1a,
                                                    const float* __restrict__ W1b,
                                                    const float* __restrict__ b1b,
                                                    float* __restrict__ h1) {
    __shared__ float sWa[3 * 64];
    __shared__ float sWb[64 * 64];
    __shared__ float sba[64], sbb[64];
    __shared__ float st_w[WPB][64];

    int tid = threadIdx.x;
    for (int i = tid; i < 3 * 64; i += BLK) sWa[i] = W1a[i];
    for (int i = tid; i < 64 * 64; i += BLK) sWb[i] = W1b[i];
    if (tid < 64) { sba[tid] = b1a[tid]; sbb[tid] = b1b[tid]; }
    __syncthreads();

    int w = tid >> 6;    // wave id in block
    int j = tid & 63;    // lane
    int nwaves = gridDim.x * WPB;

    for (int n = blockIdx.x * WPB + w; n < N_NODES; n += nwaves) {
        int start = off[n], end = off[n + 1];
        float a0 = 0.f, a1 = 0.f, a2 = 0.f;
        for (int e = start + j; e < end; e += 64) {
            int s = esrc[e];
            a0 += x[s * 3 + 0];
            a1 += x[s * 3 + 1];
            a2 += x[s * 3 + 2];
        }
#pragma unroll
        for (int d = 1; d < 64; d <<= 1) {
            a0 += __shfl_xor(a0, d);
            a1 += __shfl_xor(a1, d);
            a2 += __shfl_xor(a2, d);
        }
        float in0 = x[n * 3 + 0] + a0;
        float in1 = x[n * 3 + 1] + a1;
        float in2 = x[n * 3 + 2] + a2;
        float t = sba[j] + in0 * sWa[j] + in1 * sWa[64 + j] + in2 * sWa[128 + j];
        st_w[w][j] = fmaxf(t, 0.0f);
        __builtin_amdgcn_wave_barrier();     // order LDS write before reads (wave64 lockstep)
        float acc = sbb[j];
#pragma unroll
        for (int k = 0; k < 64; ++k) acc += st_w[w][k] * sWb[k * 64 + j];
        h1[n * 64 + j] = fmaxf(acc, 0.0f);
        __builtin_amdgcn_wave_barrier();     // order reads before next iteration's write
    }
}

// ---------------- Layer 2 fused: wave-per-node gather(h1) + MLP2 -> h2 ----------------
__global__ __launch_bounds__(1024, 8) void l2_fused(const float* __restrict__ h1,
                                                    const int* __restrict__ off,
                                                    const int* __restrict__ esrc,
                                                    const float* __restrict__ W2a,
                                                    const float* __restrict__ b2a,
                                                    const float* __restrict__ W2b,
                                                    const float* __restrict__ b2b,
                                                    float* __restrict__ h2) {
    __shared__ float sWa[64 * 64];
    __shared__ float sWb[64 * 64];
    __shared__ float sba[64], sbb[64];
    __shared__ float sin_w[WPB][64];
    __shared__ float st_w[WPB][64];

    int tid = threadIdx.x;
    for (int i = tid; i < 64 * 64; i += BLK) { sWa[i] = W2a[i]; sWb[i] = W2b[i]; }
    if (tid < 64) { sba[tid] = b2a[tid]; sbb[tid] = b2b[tid]; }
    __syncthreads();

    int w = tid >> 6;
    int j = tid & 63;
    int nwaves = gridDim.x * WPB;

    for (int n = blockIdx.x * WPB + w; n < N_NODES; n += nwaves) {
        int start = off[n], end = off[n + 1];

        float acc = h1[n * 64 + j];          // x_i + sum_{neighbors}
        int e = start;
        for (; e + 4 <= end; e += 4) {
            int s0 = esrc[e], s1 = esrc[e + 1], s2 = esrc[e + 2], s3 = esrc[e + 3];
            float v0 = h1[s0 * 64 + j];
            float v1 = h1[s1 * 64 + j];
            float v2 = h1[s2 * 64 + j];
            float v3 = h1[s3 * 64 + j];
            acc += v0 + v1 + v2 + v3;
        }
        for (; e < end; ++e) acc += h1[esrc[e] * 64 + j];

        sin_w[w][j] = acc;
        __builtin_amdgcn_wave_barrier();
        float t = sba[j];
#pragma unroll
        for (int k = 0; k < 64; ++k) t += sin_w[w][k] * sWa[k * 64 + j];
        st_w[w][j] = fmaxf(t, 0.0f);
        __builtin_amdgcn_wave_barrier();
        float o = sbb[j];
#pragma unroll
        for (int k = 0; k < 64; ++k) o += st_w[w][k] * sWb[k * 64 + j];
        h2[n * 64 + j] = fmaxf(o, 0.0f);
        __builtin_amdgcn_wave_barrier();
    }
}

// ---------------- Global mean pool ----------------
__global__ __launch_bounds__(256) void pool(const float* __restrict__ h2,
                                            const int* __restrict__ batch,
                                            float* __restrict__ out) {
    int g = blockIdx.x;
    int lo = 0, hi = N_NODES;
    while (lo < hi) { int mid = (lo + hi) >> 1; if (batch[mid] < g) lo = mid + 1; else hi = mid; }
    int start = lo;
    lo = start; hi = N_NODES;
    while (lo < hi) { int mid = (lo + hi) >> 1; if (batch[mid] < g + 1) lo = mid + 1; else hi = mid; }
    int end = lo;

    int j = threadIdx.x & 63;
    int r = threadIdx.x >> 6;
    float local = 0.0f;
    for (int n = start + r; n < end; n += 4)
        local += h2[n * 64 + j];

    __shared__ float red[4][64];
    red[r][j] = local;
    __syncthreads();
    if (r == 0) {
        float s = red[0][j] + red[1][j] + red[2][j] + red[3][j];
        float cnt = (float)((end - start) > 1 ? (end - start) : 1);
        out[g * 64 + j] = s / cnt;
    }
}

extern "C" void kernel_launch(void* const* d_in, const int* in_sizes, int n_in,
                              void* d_out, int out_size, void* d_ws, size_t ws_size,
                              hipStream_t stream) {
    const float* x    = (const float*)d_in[0];
    const int*   ei   = (const int*)d_in[1];
    const int*   bat  = (const int*)d_in[2];
    const float* W1a  = (const float*)d_in[3];
    const float* b1a  = (const float*)d_in[4];
    const float* W1b  = (const float*)d_in[5];
    const float* b1b  = (const float*)d_in[6];
    const float* W2a  = (const float*)d_in[7];
    const float* b2a  = (const float*)d_in[8];
    const float* W2b  = (const float*)d_in[9];
    const float* b2b  = (const float*)d_in[10];
    float* out = (float*)d_out;

    const int* src = ei;
    const int* dst = ei + N_EDGES;

    char* ws = (char*)d_ws;
    auto alignup = [](size_t v) { return (v + 255) & ~(size_t)255; };
    int*   deg     = (int*)ws;                      ws += alignup((size_t)N_NODES * 4);
    int*   off     = (int*)ws;                      ws += alignup((size_t)(N_NODES + 1) * 4);
    int*   cur     = (int*)ws;                      ws += alignup((size_t)N_NODES * 4);
    int*   partial = (int*)ws;                      ws += alignup((size_t)NB * 4);
    int*   esrc    = (int*)ws;                      ws += alignup((size_t)N_EDGES * 4);
    float* h1      = (float*)ws;                    ws += alignup((size_t)N_NODES * HID * 4);
    float* h2      = (float*)ws;

    hipMemsetAsync(deg, 0, (size_t)N_NODES * 4, stream);
    hipMemsetAsync(cur, 0, (size_t)N_NODES * 4, stream);

    count_deg<<<(N_EDGES + 255) / 256, 256, 0, stream>>>(dst, deg);
    scanA<<<NB, 256, 0, stream>>>(deg, partial);
    scanB<<<1, 128, 0, stream>>>(partial);
    scanC<<<NB, 256, 0, stream>>>(deg, partial, off);
    fill_csr<<<(N_EDGES + 255) / 256, 256, 0, stream>>>(src, dst, off, cur, esrc);

    l1_fused<<<NBLK, BLK, 0, stream>>>(x, off, esrc, W1a, b1a, W1b, b1b, h1);
    l2_fused<<<NBLK, BLK, 0, stream>>>(h1, off, esrc, W2a, b2a, W2b, b2b, h2);
    pool<<<N_GRAPHS, 256, 0, stream>>>(h2, bat, out);
}